// Round 1
// baseline (963.393 us; speedup 1.0000x reference)
//
#include <hip/hip_runtime.h>

typedef __attribute__((ext_vector_type(8))) __bf16 bf16x8;
typedef __attribute__((ext_vector_type(4))) __bf16 bf16x4;
typedef __attribute__((ext_vector_type(4))) float f32x4;

#define MFMA16(a,b,c) __builtin_amdgcn_mfma_f32_16x16x32_bf16(a, b, c, 0, 0, 0)

#define SS 232   // S_s / vT_s row stride (elems): 464 B = 29*16, 2-way bank alias
#define QS 40    // q_s / k_s row stride: 80 B = 5*16

__device__ inline bf16x8 bzero8() {
  bf16x8 r;
#pragma unroll
  for (int i = 0; i < 8; i++) r[i] = (__bf16)0.f;
  return r;
}

__device__ inline bf16x8 load_a_f32(const float* p) {
  const float4* q = (const float4*)p;
  float4 u = q[0], v = q[1];
  bf16x8 r;
  r[0] = (__bf16)u.x; r[1] = (__bf16)u.y; r[2] = (__bf16)u.z; r[3] = (__bf16)u.w;
  r[4] = (__bf16)v.x; r[5] = (__bf16)v.y; r[6] = (__bf16)v.z; r[7] = (__bf16)v.w;
  return r;
}

// ---------------- weight transpose/cast: wT[384][128], wpT[128][128] ---------
__global__ void k_prepw(const float* __restrict__ wq, const float* __restrict__ wkv,
                        const float* __restrict__ wproj,
                        __bf16* __restrict__ wT, __bf16* __restrict__ wpT) {
  int t = blockIdx.x * 256 + threadIdx.x;     // 65536 threads exactly
  int o = (t >> 7) & 127, i = t & 127;
  int grp = t >> 14;
  if (grp == 0)       wT[t]           = (__bf16)wq[i * 128 + o];
  else if (grp == 1)  wT[t]           = (__bf16)wkv[i * 256 + o];
  else if (grp == 2)  wT[t]           = (__bf16)wkv[i * 256 + 128 + o];
  else                wpT[t - 49152]  = (__bf16)wproj[i * 128 + o];
}

// ---------------- dynamic position bias MLP: posT[4][729] --------------------
__device__ inline void lnrelu8(float* v, const float* g, const float* bta) {
  float mu = 0.f;
#pragma unroll
  for (int i = 0; i < 8; i++) mu += v[i];
  mu *= 0.125f;
  float var = 0.f;
#pragma unroll
  for (int i = 0; i < 8; i++) { float d = v[i] - mu; var += d * d; }
  var *= 0.125f;
  float inv = rsqrtf(var + 1e-5f);
#pragma unroll
  for (int i = 0; i < 8; i++) v[i] = fmaxf((v[i] - mu) * inv * g[i] + bta[i], 0.f);
}

__global__ void k_pos(const float* __restrict__ pp_w, const float* __restrict__ pp_b,
                      const float* ln1_g, const float* ln1_b, const float* l1_w, const float* l1_b,
                      const float* ln2_g, const float* ln2_b, const float* l2_w, const float* l2_b,
                      const float* ln3_g, const float* ln3_b, const float* l3_w, const float* l3_b,
                      float* __restrict__ posT) {
  int m = blockIdx.x * blockDim.x + threadIdx.x;
  if (m >= 729) return;
  float dr = (float)(m / 27) - 13.f, dc = (float)(m % 27) - 13.f;
  float a[8], bv[8];
#pragma unroll
  for (int j = 0; j < 8; j++) a[j] = dr * pp_w[j] + dc * pp_w[8 + j] + pp_b[j];
  lnrelu8(a, ln1_g, ln1_b);
#pragma unroll
  for (int o = 0; o < 8; o++) {
    float s = l1_b[o];
#pragma unroll
    for (int j = 0; j < 8; j++) s += a[j] * l1_w[j * 8 + o];
    bv[o] = s;
  }
  lnrelu8(bv, ln2_g, ln2_b);
#pragma unroll
  for (int o = 0; o < 8; o++) {
    float s = l2_b[o];
#pragma unroll
    for (int j = 0; j < 8; j++) s += bv[j] * l2_w[j * 8 + o];
    a[o] = s;
  }
  lnrelu8(a, ln3_g, ln3_b);
#pragma unroll
  for (int o = 0; o < 4; o++) {
    float s = l3_b[o];
#pragma unroll
    for (int j = 0; j < 8; j++) s += a[j] * l3_w[j * 4 + o];
    posT[o * 729 + m] = s;
  }
}

// ---------------- fused attention: one block per (b,h) -----------------------
__launch_bounds__(512)
__global__ void k_attn(const float* __restrict__ x, const __bf16* __restrict__ wT,
                       const float* __restrict__ posT, __bf16* __restrict__ Og) {
  __shared__ __bf16 q_s[208 * QS];   // [token][d], scaled by 1/sqrt(32)
  __shared__ __bf16 k_s[208 * QS];   // [key][d]
  __shared__ __bf16 vT_s[32 * SS];   // [d][key]
  __shared__ __bf16 S_s[208 * SS];   // scores -> probabilities
  __shared__ float  pos_s[736];

  int tid = threadIdx.x;
  int wv = tid >> 6, lane = tid & 63, col = lane & 15, quad = lane >> 4;
  int bi = blockIdx.x;
  int b = (bi & 7) * 128 + ((bi >> 3) >> 2);   // same-b heads -> same XCD
  int h = (bi >> 3) & 3;

  {  // zero S_s (pad cols) and vT_s (pad keys); stage pos row
    int* ps = (int*)S_s;
    for (int i = tid; i < 208 * SS / 2; i += 512) ps[i] = 0;
    int* pv = (int*)vT_s;
    for (int i = tid; i < 32 * SS / 2; i += 512) pv[i] = 0;
    for (int i = tid; i < 729; i += 512) pos_s[i] = posT[h * 729 + i];
  }
  __syncthreads();

  // ---- Stage B: q/k/v = x_b @ W slices (13 M-tiles x 3 targets = 39 jobs)
  const float* xb = x + (size_t)b * (196 * 128);
  for (int j = wv; j < 39; j += 8) {
    int t = j / 13, mt = j % 13;
    int row = mt * 16 + col;
    bool valid = row < 196;
    const float* ap = xb + (size_t)(valid ? row : 0) * 128 + quad * 8;
    bf16x8 afr[4];
#pragma unroll
    for (int kc = 0; kc < 4; kc++) afr[kc] = valid ? load_a_f32(ap + kc * 32) : bzero8();
    float sc = (t == 0) ? 0.17677669529663687f : 1.f;
#pragma unroll
    for (int nt = 0; nt < 2; nt++) {
      const __bf16* bp = wT + (size_t)(t * 128 + h * 32 + nt * 16 + col) * 128 + quad * 8;
      f32x4 acc = {0.f, 0.f, 0.f, 0.f};
#pragma unroll
      for (int kc = 0; kc < 4; kc++) {
        bf16x8 bfr = *(const bf16x8*)(bp + kc * 32);
        acc = MFMA16(afr[kc], bfr, acc);
      }
#pragma unroll
      for (int r = 0; r < 4; r++) {
        int orow = mt * 16 + quad * 4 + r;
        int od = nt * 16 + col;
        __bf16 val = (__bf16)(acc[r] * sc);
        if (t == 0)      q_s[orow * QS + od] = val;
        else if (t == 1) k_s[orow * QS + od] = val;
        else             vT_s[od * SS + orow] = val;
      }
    }
  }
  __syncthreads();

  // ---- Stage C: S = q @ k^T + rel-pos bias (169 16x16 tiles)
  for (int j = wv; j < 169; j += 8) {
    int mt = j / 13, nt = j - mt * 13;
    bf16x8 a = *(const bf16x8*)&q_s[(mt * 16 + col) * QS + quad * 8];
    bf16x8 bb = *(const bf16x8*)&k_s[(nt * 16 + col) * QS + quad * 8];
    f32x4 acc = {0.f, 0.f, 0.f, 0.f};
    acc = MFMA16(a, bb, acc);
    int kj = nt * 16 + col;
    int r2 = kj / 14, c2 = kj - r2 * 14;
#pragma unroll
    for (int r = 0; r < 4; r++) {
      int qi = mt * 16 + quad * 4 + r;
      float s = 0.f;
      if (qi < 196 && kj < 196) {
        int r1 = qi / 14, c1 = qi - r1 * 14;
        s = acc[r] + pos_s[(r1 - r2 + 13) * 27 + (c1 - c2 + 13)];
      }
      S_s[qi * SS + kj] = (__bf16)s;
    }
  }
  __syncthreads();

  // ---- Stage D: softmax rows (fp32 stats, wave-local)
  for (int row = wv; row < 196; row += 8) {
    float xs[4] = {0.f, 0.f, 0.f, 0.f};
    int cb = lane * 4;
    bool ld = lane < 52;
    if (ld) {
      bf16x4 pv = *(const bf16x4*)&S_s[row * SS + cb];
#pragma unroll
      for (int i = 0; i < 4; i++) xs[i] = (float)pv[i];
    }
    float mx = -1e30f;
#pragma unroll
    for (int i = 0; i < 4; i++) if (ld && (cb + i) < 196) mx = fmaxf(mx, xs[i]);
#pragma unroll
    for (int off = 32; off > 0; off >>= 1) mx = fmaxf(mx, __shfl_xor(mx, off));
    float e[4]; float sm = 0.f;
#pragma unroll
    for (int i = 0; i < 4; i++) { e[i] = (ld && (cb + i) < 196) ? __expf(xs[i] - mx) : 0.f; sm += e[i]; }
#pragma unroll
    for (int off = 32; off > 0; off >>= 1) sm += __shfl_xor(sm, off);
    float inv = 1.f / sm;
    if (ld) {
      bf16x4 pv;
#pragma unroll
      for (int i = 0; i < 4; i++) pv[i] = (__bf16)(e[i] * inv);
      *(bf16x4*)&S_s[row * SS + cb] = pv;
    }
  }
  __syncthreads();

  // ---- Stage E: O = P @ V (26 jobs, K = 224)
  for (int j = wv; j < 26; j += 8) {
    int mt = j >> 1, nt = j & 1;
    f32x4 acc = {0.f, 0.f, 0.f, 0.f};
#pragma unroll
    for (int kc = 0; kc < 7; kc++) {
      bf16x8 a = *(const bf16x8*)&S_s[(mt * 16 + col) * SS + kc * 32 + quad * 8];
      bf16x8 bb = *(const bf16x8*)&vT_s[(nt * 16 + col) * SS + kc * 32 + quad * 8];
      acc = MFMA16(a, bb, acc);
    }
#pragma unroll
    for (int r = 0; r < 4; r++) {
      int gm = mt * 16 + quad * 4 + r;
      if (gm < 196)
        Og[((size_t)b * 196 + gm) * 128 + h * 32 + nt * 16 + col] = (__bf16)acc[r];
    }
  }
}

// ---------------- output projection: out = O @ wproj + bproj -----------------
__launch_bounds__(256)
__global__ void k_proj(const __bf16* __restrict__ Og, const __bf16* __restrict__ wpT,
                       const float* __restrict__ bproj, float* __restrict__ out) {
  __shared__ __bf16 A_s[64 * 136];
  int tid = threadIdx.x, wv = tid >> 6, lane = tid & 63, col = lane & 15, quad = lane >> 4;
  size_t mbase = (size_t)blockIdx.x * 64;
  for (int c = tid; c < 1024; c += 256) {   // 64 rows x 16 chunks of 8 elems
    int rr = c >> 4, cc = c & 15;
    *(bf16x8*)&A_s[rr * 136 + cc * 8] = *(const bf16x8*)&Og[(mbase + rr) * 128 + cc * 8];
  }
  __syncthreads();
  for (int j = wv; j < 32; j += 4) {        // 4 M-tiles x 8 N-tiles
    int mt = j >> 3, nt = j & 7;
    f32x4 acc = {0.f, 0.f, 0.f, 0.f};
#pragma unroll
    for (int kc = 0; kc < 4; kc++) {
      bf16x8 a = *(const bf16x8*)&A_s[(mt * 16 + col) * 136 + kc * 32 + quad * 8];
      bf16x8 bb = *(const bf16x8*)&wpT[(size_t)(nt * 16 + col) * 128 + kc * 32 + quad * 8];
      acc = MFMA16(a, bb, acc);
    }
    float bias = bproj[nt * 16 + col];
#pragma unroll
    for (int r = 0; r < 4; r++) {
      size_t gm = mbase + mt * 16 + quad * 4 + r;
      out[gm * 128 + nt * 16 + col] = acc[r] + bias;
    }
  }
}

extern "C" void kernel_launch(void* const* d_in, const int* in_sizes, int n_in,
                              void* d_out, int out_size, void* d_ws, size_t ws_size,
                              hipStream_t stream) {
  const float* x     = (const float*)d_in[0];
  const float* wq    = (const float*)d_in[1];
  const float* wkv   = (const float*)d_in[2];
  const float* wproj = (const float*)d_in[3];
  const float* bproj = (const float*)d_in[4];
  const float* pp_w  = (const float*)d_in[5];
  const float* pp_b  = (const float*)d_in[6];
  const float* ln1_g = (const float*)d_in[7];
  const float* ln1_b = (const float*)d_in[8];
  const float* l1_w  = (const float*)d_in[9];
  const float* l1_b  = (const float*)d_in[10];
  const float* ln2_g = (const float*)d_in[11];
  const float* ln2_b = (const float*)d_in[12];
  const float* l2_w  = (const float*)d_in[13];
  const float* l2_b  = (const float*)d_in[14];
  const float* ln3_g = (const float*)d_in[15];
  const float* ln3_b = (const float*)d_in[16];
  const float* l3_w  = (const float*)d_in[17];
  const float* l3_b  = (const float*)d_in[18];
  float* out = (float*)d_out;

  char* ws = (char*)d_ws;
  __bf16* wT   = (__bf16*)ws;                  // 98304 B   [384][128]
  __bf16* wpT  = (__bf16*)(ws + 98304);        // 32768 B   [128][128]
  float*  posT = (float*)(ws + 131072);        // 11776 B   [4][729]
  __bf16* Og   = (__bf16*)(ws + 143360);       // 51380224 B [B][196][128]

  k_prepw<<<256, 256, 0, stream>>>(wq, wkv, wproj, wT, wpT);
  k_pos<<<3, 256, 0, stream>>>(pp_w, pp_b, ln1_g, ln1_b, l1_w, l1_b,
                               ln2_g, ln2_b, l2_w, l2_b, ln3_g, ln3_b, l3_w, l3_b, posT);
  k_attn<<<4096, 512, 0, stream>>>(x, wT, posT, Og);
  k_proj<<<3136, 256, 0, stream>>>(Og, wpT, bproj, out);
}

// Round 2
// 531.429 us; speedup vs baseline: 1.8128x; 1.8128x over previous
//
#include <hip/hip_runtime.h>

typedef __attribute__((ext_vector_type(8))) __bf16 bf16x8;
typedef __attribute__((ext_vector_type(4))) __bf16 bf16x4;
typedef __attribute__((ext_vector_type(4))) float f32x4;

#define MFMA16(a,b,c) __builtin_amdgcn_mfma_f32_16x16x32_bf16(a, b, c, 0, 0, 0)

#define SS 232   // vT_s / p_sc row stride (elems): 464 B, bank period 8 -> 2-way (free)
#define QS 40    // k_s / q_sc row stride: 80 B
#define NW 4     // waves per block

__device__ inline bf16x8 load_a_f32(const float* p) {
  const float4* q = (const float4*)p;
  float4 u = q[0], v = q[1];
  bf16x8 r;
  r[0] = (__bf16)u.x; r[1] = (__bf16)u.y; r[2] = (__bf16)u.z; r[3] = (__bf16)u.w;
  r[4] = (__bf16)v.x; r[5] = (__bf16)v.y; r[6] = (__bf16)v.z; r[7] = (__bf16)v.w;
  return r;
}

// ---------------- weight transpose/cast: wT[384][128], wpT[128][128] ---------
__global__ void k_prepw(const float* __restrict__ wq, const float* __restrict__ wkv,
                        const float* __restrict__ wproj,
                        __bf16* __restrict__ wT, __bf16* __restrict__ wpT) {
  int t = blockIdx.x * 256 + threadIdx.x;     // 65536 threads exactly
  int o = (t >> 7) & 127, i = t & 127;
  int grp = t >> 14;
  if (grp == 0)       wT[t]           = (__bf16)wq[i * 128 + o];
  else if (grp == 1)  wT[t]           = (__bf16)wkv[i * 256 + o];
  else if (grp == 2)  wT[t]           = (__bf16)wkv[i * 256 + 128 + o];
  else                wpT[t - 49152]  = (__bf16)wproj[i * 128 + o];
}

// ---------------- dynamic position bias MLP: posT[4][729] --------------------
__device__ inline void lnrelu8(float* v, const float* g, const float* bta) {
  float mu = 0.f;
#pragma unroll
  for (int i = 0; i < 8; i++) mu += v[i];
  mu *= 0.125f;
  float var = 0.f;
#pragma unroll
  for (int i = 0; i < 8; i++) { float d = v[i] - mu; var += d * d; }
  var *= 0.125f;
  float inv = rsqrtf(var + 1e-5f);
#pragma unroll
  for (int i = 0; i < 8; i++) v[i] = fmaxf((v[i] - mu) * inv * g[i] + bta[i], 0.f);
}

__global__ void k_pos(const float* __restrict__ pp_w, const float* __restrict__ pp_b,
                      const float* ln1_g, const float* ln1_b, const float* l1_w, const float* l1_b,
                      const float* ln2_g, const float* ln2_b, const float* l2_w, const float* l2_b,
                      const float* ln3_g, const float* ln3_b, const float* l3_w, const float* l3_b,
                      float* __restrict__ posT) {
  int m = blockIdx.x * blockDim.x + threadIdx.x;
  if (m >= 729) return;
  float dr = (float)(m / 27) - 13.f, dc = (float)(m % 27) - 13.f;
  float a[8], bv[8];
#pragma unroll
  for (int j = 0; j < 8; j++) a[j] = dr * pp_w[j] + dc * pp_w[8 + j] + pp_b[j];
  lnrelu8(a, ln1_g, ln1_b);
#pragma unroll
  for (int o = 0; o < 8; o++) {
    float s = l1_b[o];
#pragma unroll
    for (int j = 0; j < 8; j++) s += a[j] * l1_w[j * 8 + o];
    bv[o] = s;
  }
  lnrelu8(bv, ln2_g, ln2_b);
#pragma unroll
  for (int o = 0; o < 8; o++) {
    float s = l2_b[o];
#pragma unroll
    for (int j = 0; j < 8; j++) s += bv[j] * l2_w[j * 8 + o];
    a[o] = s;
  }
  lnrelu8(a, ln3_g, ln3_b);
#pragma unroll
  for (int o = 0; o < 4; o++) {
    float s = l3_b[o];
#pragma unroll
    for (int j = 0; j < 8; j++) s += a[j] * l3_w[j * 4 + o];
    posT[o * 729 + m] = s;
  }
}

// ---------------- fused attention: one block (4 waves) per (b,h) -------------
// Stage B: k,v -> LDS (b64-packed epilogues), one barrier.
// Then 13 independent per-wave q-tile jobs: q-proj -> S^T tiles (softmax needs
// only 2 shfls since each lane holds one full query row) -> P to per-wave LDS
// scratch (b64) -> O^T = V^T P^T (b128 reads, dwordx2 stores). No more barriers.
__launch_bounds__(256, 2)
__global__ void k_attn(const float* __restrict__ x, const __bf16* __restrict__ wT,
                       const float* __restrict__ posT, __bf16* __restrict__ Og) {
  __shared__ __align__(16) __bf16 k_s[208 * QS];        // [key][d]      16640 B
  __shared__ __align__(16) __bf16 vT_s[32 * SS];        // [d][key]      14848 B
  __shared__ __align__(16) float  pos_s[768];           //                3072 B
  __shared__ __align__(16) __bf16 q_sc[NW][16 * QS];    // per-wave q     5120 B
  __shared__ __align__(16) __bf16 p_sc[NW][16 * SS];    // per-wave P    29696 B

  int tid = threadIdx.x;
  int wv = tid >> 6, lane = tid & 63, col = lane & 15, quad = lane >> 4;
  int bi = blockIdx.x;
  int b = (bi & 7) * 128 + (bi >> 5);   // same-b heads land on same XCD
  int h = (bi >> 3) & 3;

  bf16x4 bz4;
#pragma unroll
  for (int i = 0; i < 4; i++) bz4[i] = (__bf16)0.f;

  // zero vT_s key-columns 208..231 (never written; must not be NaN under P=0)
  if (tid < 192) {
    int r = tid / 6, c = tid - r * 6;
    *(bf16x4*)&vT_s[r * SS + 208 + c * 4] = bz4;
  }
  for (int i = tid; i < 768; i += 256) pos_s[i] = (i < 729) ? posT[h * 729 + i] : 0.f;

  // ---- Stage B: k and v projections into LDS (26 jobs)
  const float* xb = x + (size_t)b * (196 * 128);
  for (int j = wv; j < 26; j += NW) {
    int t = (j >= 13) ? 1 : 0;          // 0 = k, 1 = v (wave-uniform)
    int mt = j - t * 13;
    int row = mt * 16 + col;
    const float* ap = xb + (size_t)(row < 196 ? row : 0) * 128 + quad * 8;
    bf16x8 xf[4];
#pragma unroll
    for (int kc = 0; kc < 4; kc++) xf[kc] = load_a_f32(ap + kc * 32);
    const __bf16* wbase = wT + (size_t)(128 + t * 128 + h * 32) * 128;
#pragma unroll
    for (int nt = 0; nt < 2; nt++) {
      f32x4 acc = {0.f, 0.f, 0.f, 0.f};
      if (t == 0) {   // k, swapped orientation: D[od][token]
#pragma unroll
        for (int kc = 0; kc < 4; kc++)
          acc = MFMA16(*(const bf16x8*)(wbase + (size_t)(nt * 16 + col) * 128 + kc * 32 + quad * 8),
                       xf[kc], acc);
        bf16x4 pk;
#pragma unroll
        for (int r = 0; r < 4; r++) pk[r] = (__bf16)acc[r];
        *(bf16x4*)&k_s[(mt * 16 + col) * QS + nt * 16 + quad * 4] = pk;
      } else {        // v, normal orientation: D[token][od] -> vT_s[od][token]
#pragma unroll
        for (int kc = 0; kc < 4; kc++)
          acc = MFMA16(xf[kc],
                       *(const bf16x8*)(wbase + (size_t)(nt * 16 + col) * 128 + kc * 32 + quad * 8),
                       acc);
        bf16x4 pk;
#pragma unroll
        for (int r = 0; r < 4; r++) pk[r] = (__bf16)acc[r];
        *(bf16x4*)&vT_s[(nt * 16 + col) * SS + mt * 16 + quad * 4] = pk;
      }
    }
  }
  __syncthreads();

  // ---- Per-wave q-tile jobs
  __bf16* myq = &q_sc[wv][0];
  __bf16* myp = &p_sc[wv][0];
  const float scale = 0.17677669529663687f;   // 32^-0.5

  for (int qt = wv; qt < 13; qt += NW) {
    // q projection into per-wave scratch (swapped: D[od][token])
    int row = qt * 16 + col;
    const float* ap = xb + (size_t)(row < 196 ? row : 0) * 128 + quad * 8;
    bf16x8 xf[4];
#pragma unroll
    for (int kc = 0; kc < 4; kc++) xf[kc] = load_a_f32(ap + kc * 32);
#pragma unroll
    for (int nt = 0; nt < 2; nt++) {
      f32x4 acc = {0.f, 0.f, 0.f, 0.f};
#pragma unroll
      for (int kc = 0; kc < 4; kc++)
        acc = MFMA16(*(const bf16x8*)(wT + (size_t)(h * 32 + nt * 16 + col) * 128 + kc * 32 + quad * 8),
                     xf[kc], acc);
      bf16x4 pk;
#pragma unroll
      for (int r = 0; r < 4; r++) pk[r] = (__bf16)(acc[r] * scale);
      *(bf16x4*)&myq[col * QS + nt * 16 + quad * 4] = pk;
    }
    asm volatile("s_waitcnt lgkmcnt(0)" ::: "memory");
    bf16x8 qf = *(const bf16x8*)&myq[col * QS + quad * 8];

    // S^T tiles: D[kj][qi], lane holds one qi = qt*16+col across all kj
    f32x4 sv[13];
#pragma unroll
    for (int kt = 0; kt < 13; kt++) {
      bf16x8 kf = *(const bf16x8*)&k_s[(kt * 16 + col) * QS + quad * 8];
      f32x4 z = {0.f, 0.f, 0.f, 0.f};
      sv[kt] = MFMA16(kf, qf, z);
    }

    // bias + row max (in-lane over 52 + 2 shfls)
    int qi = qt * 16 + col;
    int r1 = (qi * 4682) >> 16; int c1 = qi - r1 * 14;
    int base = (r1 + 13) * 27 + c1 + 13;
    float mx = -3.0e38f;
#pragma unroll
    for (int kt = 0; kt < 13; kt++) {
      int kb = kt * 16 + quad * 4;
#pragma unroll
      for (int r = 0; r < 4; r++) {
        int kj = kb + r;
        int r2 = (kj * 4682) >> 16; int c2 = kj - r2 * 14;
        int idx = base - r2 * 27 - c2;
        idx = idx < 0 ? 0 : idx;
        float s = (kj < 196) ? (sv[kt][r] + pos_s[idx]) : -3.0e38f;
        sv[kt][r] = s;
        mx = fmaxf(mx, s);
      }
    }
    mx = fmaxf(mx, __shfl_xor(mx, 16));
    mx = fmaxf(mx, __shfl_xor(mx, 32));

    // exp, sum, pack P (unnormalized; normalize O at the end)
    float sum = 0.f;
#pragma unroll
    for (int kt = 0; kt < 13; kt++) {
      bf16x4 pk;
#pragma unroll
      for (int r = 0; r < 4; r++) {
        float e = __expf(sv[kt][r] - mx);
        sum += e;
        pk[r] = (__bf16)e;
      }
      *(bf16x4*)&myp[col * SS + kt * 16 + quad * 4] = pk;
    }
    *(bf16x4*)&myp[col * SS + 208 + quad * 4] = bz4;   // kj 208..223 = 0
    sum += __shfl_xor(sum, 16);
    sum += __shfl_xor(sum, 32);
    float inv = 1.f / sum;
    asm volatile("s_waitcnt lgkmcnt(0)" ::: "memory");

    // O^T = V^T P^T : D[d][qi]
    f32x4 o0 = {0.f, 0.f, 0.f, 0.f}, o1 = {0.f, 0.f, 0.f, 0.f};
#pragma unroll
    for (int kc = 0; kc < 7; kc++) {
      bf16x8 pf = *(const bf16x8*)&myp[col * SS + kc * 32 + quad * 8];
      bf16x8 v0 = *(const bf16x8*)&vT_s[col * SS + kc * 32 + quad * 8];
      bf16x8 v1 = *(const bf16x8*)&vT_s[(16 + col) * SS + kc * 32 + quad * 8];
      o0 = MFMA16(v0, pf, o0);
      o1 = MFMA16(v1, pf, o1);
    }
    if (qi < 196) {
      __bf16* og = Og + ((size_t)b * 196 + qi) * 128 + h * 32;
      bf16x4 s0, s1;
#pragma unroll
      for (int r = 0; r < 4; r++) {
        s0[r] = (__bf16)(o0[r] * inv);
        s1[r] = (__bf16)(o1[r] * inv);
      }
      *(bf16x4*)&og[quad * 4]      = s0;
      *(bf16x4*)&og[16 + quad * 4] = s1;
    }
  }
}

// ---------------- output projection: out = O @ wproj + bproj -----------------
__launch_bounds__(256)
__global__ void k_proj(const __bf16* __restrict__ Og, const __bf16* __restrict__ wpT,
                       const float* __restrict__ bproj, float* __restrict__ out) {
  __shared__ __align__(16) __bf16 A_s[64 * 136];
  __shared__ float bp_s[128];
  int tid = threadIdx.x, wv = tid >> 6, lane = tid & 63, col = lane & 15, quad = lane >> 4;
  size_t mbase = (size_t)blockIdx.x * 64;
  if (tid < 128) bp_s[tid] = bproj[tid];
  for (int c = tid; c < 1024; c += 256) {
    int rr = c >> 4, cc = c & 15;
    *(bf16x8*)&A_s[rr * 136 + cc * 8] = *(const bf16x8*)&Og[(mbase + rr) * 128 + cc * 8];
  }
  __syncthreads();
  for (int j = wv; j < 32; j += 4) {    // 4 M-tiles x 8 N-tiles, swapped: D[od][token]
    int mt = j >> 3, nt = j & 7;
    f32x4 acc = {0.f, 0.f, 0.f, 0.f};
#pragma unroll
    for (int kc = 0; kc < 4; kc++)
      acc = MFMA16(*(const bf16x8*)&wpT[(size_t)(nt * 16 + col) * 128 + kc * 32 + quad * 8],
                   *(const bf16x8*)&A_s[(mt * 16 + col) * 136 + kc * 32 + quad * 8],
                   acc);
    int od = nt * 16 + quad * 4;
    float4 st = { acc[0] + bp_s[od], acc[1] + bp_s[od + 1],
                  acc[2] + bp_s[od + 2], acc[3] + bp_s[od + 3] };
    size_t rw = mbase + mt * 16 + col;
    *(float4*)&out[rw * 128 + od] = st;
  }
}

extern "C" void kernel_launch(void* const* d_in, const int* in_sizes, int n_in,
                              void* d_out, int out_size, void* d_ws, size_t ws_size,
                              hipStream_t stream) {
  const float* x     = (const float*)d_in[0];
  const float* wq    = (const float*)d_in[1];
  const float* wkv   = (const float*)d_in[2];
  const float* wproj = (const float*)d_in[3];
  const float* bproj = (const float*)d_in[4];
  const float* pp_w  = (const float*)d_in[5];
  const float* pp_b  = (const float*)d_in[6];
  const float* ln1_g = (const float*)d_in[7];
  const float* ln1_b = (const float*)d_in[8];
  const float* l1_w  = (const float*)d_in[9];
  const float* l1_b  = (const float*)d_in[10];
  const float* ln2_g = (const float*)d_in[11];
  const float* ln2_b = (const float*)d_in[12];
  const float* l2_w  = (const float*)d_in[13];
  const float* l2_b  = (const float*)d_in[14];
  const float* ln3_g = (const float*)d_in[15];
  const float* ln3_b = (const float*)d_in[16];
  const float* l3_w  = (const float*)d_in[17];
  const float* l3_b  = (const float*)d_in[18];
  float* out = (float*)d_out;

  char* ws = (char*)d_ws;
  __bf16* wT   = (__bf16*)ws;                  // 98304 B   [384][128]
  __bf16* wpT  = (__bf16*)(ws + 98304);        // 32768 B   [128][128]
  float*  posT = (float*)(ws + 131072);        // 11776 B   [4][729]
  __bf16* Og   = (__bf16*)(ws + 143360);       // 51380224 B [B][196][128]

  k_prepw<<<256, 256, 0, stream>>>(wq, wkv, wproj, wT, wpT);
  k_pos<<<3, 256, 0, stream>>>(pp_w, pp_b, ln1_g, ln1_b, l1_w, l1_b,
                               ln2_g, ln2_b, l2_w, l2_b, ln3_g, ln3_b, l3_w, l3_b, posT);
  k_attn<<<4096, 256, 0, stream>>>(x, wT, posT, Og);
  k_proj<<<3136, 256, 0, stream>>>(Og, wpT, bproj, out);
}

// Round 3
// 488.861 us; speedup vs baseline: 1.9707x; 1.0871x over previous
//
#include <hip/hip_runtime.h>

typedef __attribute__((ext_vector_type(8))) __bf16 bf16x8;
typedef __attribute__((ext_vector_type(4))) __bf16 bf16x4;
typedef __attribute__((ext_vector_type(4))) float f32x4;
typedef __attribute__((ext_vector_type(4))) short s16x4;

#define MFMA32(a,b,c) __builtin_amdgcn_mfma_f32_16x16x32_bf16(a, b, c, 0, 0, 0)

static __device__ inline f32x4 MFMAX16(s16x4 a, s16x4 b, f32x4 c) {
#if __has_builtin(__builtin_amdgcn_mfma_f32_16x16x16bf16_1k)
  return __builtin_amdgcn_mfma_f32_16x16x16bf16_1k(a, b, c, 0, 0, 0);
#else
  f32x4 d;
  asm("v_mfma_f32_16x16x16_bf16 %0, %1, %2, %3" : "=v"(d) : "v"(a), "v"(b), "v"(c));
  return d;
#endif
}

#define KS 36    // k_s row stride (elems): 72 B -> 16 distinct even banks, conflict-free b64
#define VS 212   // vT_s row stride (elems): 424 B -> same property
#define NW 4     // waves per block

__device__ inline bf16x8 load_a_f32(const float* p) {
  const float4* q = (const float4*)p;
  float4 u = q[0], v = q[1];
  bf16x8 r;
  r[0] = (__bf16)u.x; r[1] = (__bf16)u.y; r[2] = (__bf16)u.z; r[3] = (__bf16)u.w;
  r[4] = (__bf16)v.x; r[5] = (__bf16)v.y; r[6] = (__bf16)v.z; r[7] = (__bf16)v.w;
  return r;
}

// ---- weight prep: frag-major attn weights wF[h][t][nt][kc][lane][8] + wpT ---
__global__ void k_prepw(const float* __restrict__ wq, const float* __restrict__ wkv,
                        const float* __restrict__ wproj,
                        __bf16* __restrict__ wF, __bf16* __restrict__ wpT) {
  int t = blockIdx.x * 256 + threadIdx.x;
  if (t < 6144) {          // 96 frags x 64 lanes; frag = ((h*3+tt)*2+nt)*4+kc
    int lane = t & 63, frag = t >> 6;
    int kc = frag & 3, nt = (frag >> 2) & 1, tt = (frag >> 3) % 3, h = frag / 24;
    int col = lane & 15, quad = lane >> 4;
    int o = h * 32 + nt * 16 + col;
    int ibase = kc * 32 + quad * 8;
    bf16x8 vv;
#pragma unroll
    for (int j = 0; j < 8; j++) {
      int in = ibase + j;
      float w = (tt == 0) ? wq[in * 128 + o]
              : (tt == 1) ? wkv[in * 256 + o]
                          : wkv[in * 256 + 128 + o];
      vv[j] = (__bf16)w;
    }
    *(bf16x8*)&wF[(size_t)t * 8] = vv;
  } else if (t < 6144 + 16384) {
    int t2 = t - 6144;
    int o = t2 >> 7, i = t2 & 127;
    wpT[t2] = (__bf16)wproj[i * 128 + o];
  }
}

// ---------------- dynamic position bias MLP: posT[4][729] --------------------
__device__ inline void lnrelu8(float* v, const float* g, const float* bta) {
  float mu = 0.f;
#pragma unroll
  for (int i = 0; i < 8; i++) mu += v[i];
  mu *= 0.125f;
  float var = 0.f;
#pragma unroll
  for (int i = 0; i < 8; i++) { float d = v[i] - mu; var += d * d; }
  var *= 0.125f;
  float inv = rsqrtf(var + 1e-5f);
#pragma unroll
  for (int i = 0; i < 8; i++) v[i] = fmaxf((v[i] - mu) * inv * g[i] + bta[i], 0.f);
}

__global__ void k_pos(const float* __restrict__ pp_w, const float* __restrict__ pp_b,
                      const float* ln1_g, const float* ln1_b, const float* l1_w, const float* l1_b,
                      const float* ln2_g, const float* ln2_b, const float* l2_w, const float* l2_b,
                      const float* ln3_g, const float* ln3_b, const float* l3_w, const float* l3_b,
                      float* __restrict__ posT) {
  int m = blockIdx.x * blockDim.x + threadIdx.x;
  if (m >= 729) return;
  float dr = (float)(m / 27) - 13.f, dc = (float)(m % 27) - 13.f;
  float a[8], bv[8];
#pragma unroll
  for (int j = 0; j < 8; j++) a[j] = dr * pp_w[j] + dc * pp_w[8 + j] + pp_b[j];
  lnrelu8(a, ln1_g, ln1_b);
#pragma unroll
  for (int o = 0; o < 8; o++) {
    float s = l1_b[o];
#pragma unroll
    for (int j = 0; j < 8; j++) s += a[j] * l1_w[j * 8 + o];
    bv[o] = s;
  }
  lnrelu8(bv, ln2_g, ln2_b);
#pragma unroll
  for (int o = 0; o < 8; o++) {
    float s = l2_b[o];
#pragma unroll
    for (int j = 0; j < 8; j++) s += bv[j] * l2_w[j * 8 + o];
    a[o] = s;
  }
  lnrelu8(a, ln3_g, ln3_b);
#pragma unroll
  for (int o = 0; o < 4; o++) {
    float s = l3_b[o];
#pragma unroll
    for (int j = 0; j < 8; j++) s += a[j] * l3_w[j * 4 + o];
    posT[o * 729 + m] = s;
  }
}

// ---- bias table: biasT[h][qi<208][kj<208] bf16, 0 outside valid range -------
__global__ void k_bias(const float* __restrict__ posT, __bf16* __restrict__ biasT) {
  int t = blockIdx.x * 256 + threadIdx.x;
  if (t >= 4 * 208 * 52) return;
  int g = t % 52; int rem = t / 52; int qi = rem % 208; int h = rem / 208;
  int kj0 = g * 4;
  int r1 = qi / 14, c1 = qi % 14;
  bf16x4 o;
#pragma unroll
  for (int r = 0; r < 4; r++) {
    int kj = kj0 + r;
    float v = 0.f;
    if (qi < 196 && kj < 196) {
      int r2 = kj / 14, c2 = kj % 14;
      v = posT[h * 729 + (r1 - r2 + 13) * 27 + (c1 - c2 + 13)];
    }
    o[r] = (__bf16)v;
  }
  *(bf16x4*)&biasT[((size_t)(h * 208 + qi)) * 208 + kj0] = o;
}

// ---------------- fused attention: one block (4 waves) per (b,h) -------------
// Key identity: 16x16x16 MFMA B-layout == 16x16 C/D layout, so q-proj output
// feeds S^T directly and P (exp of S^T) feeds PV directly — zero LDS
// round-trips in the q-loop, no intra-wave lgkmcnt serialization.
__launch_bounds__(256, 3)
__global__ void k_attn(const float* __restrict__ x, const __bf16* __restrict__ wF,
                       const __bf16* __restrict__ biasT, __bf16* __restrict__ Og) {
  __shared__ __align__(16) __bf16 wF_s[12288];      // 24576 B frag-major q,k,v weights
  __shared__ __align__(16) __bf16 k_s[208 * KS];    // 14976 B [token][d]
  __shared__ __align__(16) __bf16 vT_s[32 * VS];    // 13568 B [d][token]

  int tid = threadIdx.x;
  int wv = tid >> 6, lane = tid & 63, col = lane & 15, quad = lane >> 4;
  int bi = blockIdx.x;
  int b = (bi & 7) * 128 + (bi >> 5);   // same-b heads -> same XCD
  int h = (bi >> 3) & 3;

  {  // stage this head's weight frags (24 KB from L2, coalesced)
    const bf16x8* src = (const bf16x8*)(wF + (size_t)h * 12288);
    bf16x8* dst = (bf16x8*)wF_s;
    for (int i = tid; i < 1536; i += 256) dst[i] = src[i];
  }
  __syncthreads();

#define WFRAG(t, nt, kc) (*(const bf16x8*)&wF_s[(((t) * 2 + (nt)) * 4 + (kc)) * 512 + lane * 8])

  const float* xb = x + (size_t)b * (196 * 128);

  // ---- Stage B: k and v projections into LDS (x loaded once per row-tile)
  for (int j = wv; j < 13; j += NW) {
    int row = j * 16 + col;
    const float* ap = xb + (size_t)(row < 196 ? row : 0) * 128 + quad * 8;
    bf16x8 xf[4];
#pragma unroll
    for (int kc = 0; kc < 4; kc++) xf[kc] = load_a_f32(ap + kc * 32);
#pragma unroll
    for (int nt = 0; nt < 2; nt++) {       // k, swapped: D[od][token]
      f32x4 acc = {0.f, 0.f, 0.f, 0.f};
#pragma unroll
      for (int kc = 0; kc < 4; kc++) acc = MFMA32(WFRAG(1, nt, kc), xf[kc], acc);
      bf16x4 pk;
#pragma unroll
      for (int r = 0; r < 4; r++) pk[r] = (__bf16)acc[r];
      *(bf16x4*)&k_s[(j * 16 + col) * KS + nt * 16 + quad * 4] = pk;
    }
#pragma unroll
    for (int nt = 0; nt < 2; nt++) {       // v, normal: D[token][od] -> vT_s[od][token]
      f32x4 acc = {0.f, 0.f, 0.f, 0.f};
#pragma unroll
      for (int kc = 0; kc < 4; kc++) acc = MFMA32(xf[kc], WFRAG(2, nt, kc), acc);
      bf16x4 pk;
#pragma unroll
      for (int r = 0; r < 4; r++) pk[r] = (__bf16)acc[r];
      *(bf16x4*)&vT_s[(nt * 16 + col) * VS + j * 16 + quad * 4] = pk;
    }
  }
  __syncthreads();

  const float scale = 0.17677669529663687f;   // 32^-0.5

  // ---- per-wave q-tile jobs: fully register-resident pipeline
  for (int qt = wv; qt < 13; qt += NW) {
    int qi = qt * 16 + col;
    const float* ap = xb + (size_t)(qi < 196 ? qi : 0) * 128 + quad * 8;
    bf16x8 xf[4];
#pragma unroll
    for (int kc = 0; kc < 4; kc++) xf[kc] = load_a_f32(ap + kc * 32);

    s16x4 qb[2];                             // q B-frags for 16x16x16 (d = nt*16+quad*4+j)
#pragma unroll
    for (int nt = 0; nt < 2; nt++) {
      f32x4 acc = {0.f, 0.f, 0.f, 0.f};
#pragma unroll
      for (int kc = 0; kc < 4; kc++) acc = MFMA32(WFRAG(0, nt, kc), xf[kc], acc);
      bf16x4 pk;
#pragma unroll
      for (int r = 0; r < 4; r++) pk[r] = (__bf16)(acc[r] * scale);
      qb[nt] = __builtin_bit_cast(s16x4, pk);
    }

    // preload bias row (L2)
    const __bf16* brow = biasT + ((size_t)(h * 208 + qi)) * 208 + quad * 4;
    bf16x4 bl[13];
#pragma unroll
    for (int kt = 0; kt < 13; kt++) bl[kt] = *(const bf16x4*)(brow + kt * 16);

    // S^T tiles -> bias -> exp -> pack P (no-max softmax, fp32 sum)
    float sum = 0.f;
    s16x4 pp[13];
#pragma unroll
    for (int kt = 0; kt < 13; kt++) {
      s16x4 ka0 = *(const s16x4*)&k_s[(kt * 16 + col) * KS + quad * 4];
      s16x4 ka1 = *(const s16x4*)&k_s[(kt * 16 + col) * KS + 16 + quad * 4];
      f32x4 acc = {0.f, 0.f, 0.f, 0.f};
      acc = MFMAX16(ka0, qb[0], acc);
      acc = MFMAX16(ka1, qb[1], acc);
      bf16x4 pk;
#pragma unroll
      for (int r = 0; r < 4; r++) {
        float e = __expf(acc[r] + (float)bl[kt][r]);
        if (kt == 12 && quad != 0) e = 0.f;   // kj >= 196 masked
        sum += e;
        pk[r] = (__bf16)e;
      }
      pp[kt] = __builtin_bit_cast(s16x4, pk);
    }
    sum += __shfl_xor(sum, 16);
    sum += __shfl_xor(sum, 32);
    float inv = 1.f / sum;

    // O^T = V^T P^T via 16x16x16 (P frags straight from registers)
    f32x4 o0 = {0.f, 0.f, 0.f, 0.f}, o1 = {0.f, 0.f, 0.f, 0.f};
#pragma unroll
    for (int kt = 0; kt < 13; kt++) {
      s16x4 va0 = *(const s16x4*)&vT_s[col * VS + kt * 16 + quad * 4];
      s16x4 va1 = *(const s16x4*)&vT_s[(16 + col) * VS + kt * 16 + quad * 4];
      o0 = MFMAX16(va0, pp[kt], o0);
      o1 = MFMAX16(va1, pp[kt], o1);
    }
    if (qi < 196) {
      __bf16* og = Og + ((size_t)b * 196 + qi) * 128 + h * 32;
      bf16x4 s0, s1;
#pragma unroll
      for (int r = 0; r < 4; r++) {
        s0[r] = (__bf16)(o0[r] * inv);
        s1[r] = (__bf16)(o1[r] * inv);
      }
      *(bf16x4*)&og[quad * 4]      = s0;
      *(bf16x4*)&og[16 + quad * 4] = s1;
    }
  }
#undef WFRAG
}

// ---------------- output projection: out = O @ wproj + bproj -----------------
__launch_bounds__(256)
__global__ void k_proj(const __bf16* __restrict__ Og, const __bf16* __restrict__ wpT,
                       const float* __restrict__ bproj, float* __restrict__ out) {
  __shared__ __align__(16) __bf16 A_s[64 * 136];
  __shared__ float bp_s[128];
  int tid = threadIdx.x, wv = tid >> 6, lane = tid & 63, col = lane & 15, quad = lane >> 4;
  size_t mbase = (size_t)blockIdx.x * 64;
  if (tid < 128) bp_s[tid] = bproj[tid];
  for (int c = tid; c < 1024; c += 256) {
    int rr = c >> 4, cc = c & 15;
    *(bf16x8*)&A_s[rr * 136 + cc * 8] = *(const bf16x8*)&Og[(mbase + rr) * 128 + cc * 8];
  }
  __syncthreads();
  for (int j = wv; j < 32; j += 4) {    // 4 M-tiles x 8 N-tiles, swapped: D[od][token]
    int mt = j >> 3, nt = j & 7;
    f32x4 acc = {0.f, 0.f, 0.f, 0.f};
#pragma unroll
    for (int kc = 0; kc < 4; kc++)
      acc = MFMA32(*(const bf16x8*)&wpT[(size_t)(nt * 16 + col) * 128 + kc * 32 + quad * 8],
                   *(const bf16x8*)&A_s[(mt * 16 + col) * 136 + kc * 32 + quad * 8],
                   acc);
    int od = nt * 16 + quad * 4;
    float4 st = { acc[0] + bp_s[od], acc[1] + bp_s[od + 1],
                  acc[2] + bp_s[od + 2], acc[3] + bp_s[od + 3] };
    size_t rw = mbase + mt * 16 + col;
    *(float4*)&out[rw * 128 + od] = st;
  }
}

extern "C" void kernel_launch(void* const* d_in, const int* in_sizes, int n_in,
                              void* d_out, int out_size, void* d_ws, size_t ws_size,
                              hipStream_t stream) {
  const float* x     = (const float*)d_in[0];
  const float* wq    = (const float*)d_in[1];
  const float* wkv   = (const float*)d_in[2];
  const float* wproj = (const float*)d_in[3];
  const float* bproj = (const float*)d_in[4];
  const float* pp_w  = (const float*)d_in[5];
  const float* pp_b  = (const float*)d_in[6];
  const float* ln1_g = (const float*)d_in[7];
  const float* ln1_b = (const float*)d_in[8];
  const float* l1_w  = (const float*)d_in[9];
  const float* l1_b  = (const float*)d_in[10];
  const float* ln2_g = (const float*)d_in[11];
  const float* ln2_b = (const float*)d_in[12];
  const float* l2_w  = (const float*)d_in[13];
  const float* l2_b  = (const float*)d_in[14];
  const float* ln3_g = (const float*)d_in[15];
  const float* ln3_b = (const float*)d_in[16];
  const float* l3_w  = (const float*)d_in[17];
  const float* l3_b  = (const float*)d_in[18];
  float* out = (float*)d_out;

  char* ws = (char*)d_ws;
  __bf16* wF    = (__bf16*)ws;                  //  98304 B  [4][3][2][4][64][8]
  __bf16* wpT   = (__bf16*)(ws + 98304);        //  32768 B  [128][128]
  float*  posT  = (float*)(ws + 131072);        //  11664 B  [4][729]
  __bf16* biasT = (__bf16*)(ws + 143360);       // 346112 B  [4][208][208]
  __bf16* Og    = (__bf16*)(ws + 489472);       // 51380224 B [B][196][128]

  k_prepw<<<88, 256, 0, stream>>>(wq, wkv, wproj, wF, wpT);
  k_pos<<<3, 256, 0, stream>>>(pp_w, pp_b, ln1_g, ln1_b, l1_w, l1_b,
                               ln2_g, ln2_b, l2_w, l2_b, ln3_g, ln3_b, l3_w, l3_b, posT);
  k_bias<<<169, 256, 0, stream>>>(posT, biasT);
  k_attn<<<4096, 256, 0, stream>>>(x, wF, biasT, Og);
  k_proj<<<3136, 256, 0, stream>>>(Og, wpT, bproj, out);
}

// Round 4
// 382.100 us; speedup vs baseline: 2.5213x; 1.2794x over previous
//
#include <hip/hip_runtime.h>

typedef __attribute__((ext_vector_type(8))) __bf16 bf16x8;
typedef __attribute__((ext_vector_type(4))) __bf16 bf16x4;
typedef __attribute__((ext_vector_type(4))) float f32x4;
typedef __attribute__((ext_vector_type(4))) short s16x4;

#define MFMA32(a,b,c) __builtin_amdgcn_mfma_f32_16x16x32_bf16(a, b, c, 0, 0, 0)

static __device__ inline f32x4 MFMAX16(s16x4 a, s16x4 b, f32x4 c) {
#if __has_builtin(__builtin_amdgcn_mfma_f32_16x16x16bf16_1k)
  return __builtin_amdgcn_mfma_f32_16x16x16bf16_1k(a, b, c, 0, 0, 0);
#else
  f32x4 d;
  asm("v_mfma_f32_16x16x16_bf16 %0, %1, %2, %3" : "=v"(d) : "v"(a), "v"(b), "v"(c));
  return d;
#endif
}

#define KS 36    // k_s row stride (elems)
#define VS 212   // vT_s row stride (elems)
#define NW 4     // waves per block

__device__ inline bf16x8 load_a_f32(const float* p) {
  const float4* q = (const float4*)p;
  float4 u = q[0], v = q[1];
  bf16x8 r;
  r[0] = (__bf16)u.x; r[1] = (__bf16)u.y; r[2] = (__bf16)u.z; r[3] = (__bf16)u.w;
  r[4] = (__bf16)v.x; r[5] = (__bf16)v.y; r[6] = (__bf16)v.z; r[7] = (__bf16)v.w;
  return r;
}

__device__ inline void lnrelu8(float* v, const float* g, const float* bta) {
  float mu = 0.f;
#pragma unroll
  for (int i = 0; i < 8; i++) mu += v[i];
  mu *= 0.125f;
  float var = 0.f;
#pragma unroll
  for (int i = 0; i < 8; i++) { float d = v[i] - mu; var += d * d; }
  var *= 0.125f;
  float inv = rsqrtf(var + 1e-5f);
#pragma unroll
  for (int i = 0; i < 8; i++) v[i] = fmaxf((v[i] - mu) * inv * g[i] + bta[i], 0.f);
}

// ---- merged prep: blocks 0..87 weight repack; blocks 88..256 pos-MLP + bias table
__global__ void k_prep(const float* __restrict__ wq, const float* __restrict__ wkv,
                       const float* __restrict__ wproj,
                       const float* __restrict__ pp_w, const float* __restrict__ pp_b,
                       const float* ln1_g, const float* ln1_b, const float* l1_w, const float* l1_b,
                       const float* ln2_g, const float* ln2_b, const float* l2_w, const float* l2_b,
                       const float* ln3_g, const float* ln3_b, const float* l3_w, const float* l3_b,
                       __bf16* __restrict__ wF, __bf16* __restrict__ wpT,
                       __bf16* __restrict__ biasT) {
  __shared__ float pos_s[4 * 729];
  int blk = blockIdx.x, tid = threadIdx.x;
  if (blk < 88) {
    int t = blk * 256 + tid;
    if (t < 6144) {          // 96 frags x 64 lanes; frag = ((h*3+tt)*2+nt)*4+kc
      int lane = t & 63, frag = t >> 6;
      int kc = frag & 3, nt = (frag >> 2) & 1, tt = (frag >> 3) % 3, h = frag / 24;
      int col = lane & 15, quad = lane >> 4;
      int o = h * 32 + nt * 16 + col;
      int ibase = kc * 32 + quad * 8;
      bf16x8 vv;
#pragma unroll
      for (int j = 0; j < 8; j++) {
        int in = ibase + j;
        float w = (tt == 0) ? wq[in * 128 + o]
                : (tt == 1) ? wkv[in * 256 + o]
                            : wkv[in * 256 + 128 + o];
        vv[j] = (__bf16)w;
      }
      *(bf16x8*)&wF[(size_t)t * 8] = vv;
    } else if (t < 6144 + 16384) {
      int t2 = t - 6144;
      int o = t2 >> 7, i = t2 & 127;
      wpT[t2] = (__bf16)wproj[i * 128 + o];
    }
    return;
  }
  // bias blocks: recompute the tiny pos MLP into LDS, then emit bias slice
  for (int m = tid; m < 729; m += 256) {
    float dr = (float)(m / 27) - 13.f, dc = (float)(m % 27) - 13.f;
    float a[8], bv[8];
#pragma unroll
    for (int j = 0; j < 8; j++) a[j] = dr * pp_w[j] + dc * pp_w[8 + j] + pp_b[j];
    lnrelu8(a, ln1_g, ln1_b);
#pragma unroll
    for (int o = 0; o < 8; o++) {
      float s = l1_b[o];
#pragma unroll
      for (int j = 0; j < 8; j++) s += a[j] * l1_w[j * 8 + o];
      bv[o] = s;
    }
    lnrelu8(bv, ln2_g, ln2_b);
#pragma unroll
    for (int o = 0; o < 8; o++) {
      float s = l2_b[o];
#pragma unroll
      for (int j = 0; j < 8; j++) s += bv[j] * l2_w[j * 8 + o];
      a[o] = s;
    }
    lnrelu8(a, ln3_g, ln3_b);
#pragma unroll
    for (int o = 0; o < 4; o++) {
      float s = l3_b[o];
#pragma unroll
      for (int j = 0; j < 8; j++) s += a[j] * l3_w[j * 4 + o];
      pos_s[o * 729 + m] = s;
    }
  }
  __syncthreads();
  int t = (blk - 88) * 256 + tid;           // 169*256 == 4*208*52 exactly
  int g = t % 52; int rem = t / 52; int qi = rem % 208; int h = rem / 208;
  int kj0 = g * 4;
  int r1 = qi / 14, c1 = qi % 14;
  bf16x4 o;
#pragma unroll
  for (int r = 0; r < 4; r++) {
    int kj = kj0 + r;
    float v = 0.f;
    if (qi < 196 && kj < 196) {
      int r2 = kj / 14, c2 = kj % 14;
      v = pos_s[h * 729 + (r1 - r2 + 13) * 27 + (c1 - c2 + 13)];
    }
    o[r] = (__bf16)v;
  }
  *(bf16x4*)&biasT[((size_t)(h * 208 + qi)) * 208 + kj0] = o;
}

// ---------------- fused attention: one block (4 waves) per (b,h) -------------
// x loaded ONCE per block: stage B computes k,v (->LDS) and q (->registers,
// 16x16x16 B-frag layout == C/D layout identity) from the same x fragments.
// q-phase: only global traffic is 13x8B bias rows, prefetched ahead of the
// S^T MFMAs that don't depend on them.
__launch_bounds__(256, 4)
__global__ void k_attn(const float* __restrict__ x, const __bf16* __restrict__ wF,
                       const __bf16* __restrict__ biasT, __bf16* __restrict__ Og) {
  __shared__ __align__(16) __bf16 k_s[208 * KS];    // 14976 B [token][d]
  __shared__ __align__(16) __bf16 vT_s[32 * VS];    // 13568 B [d][token]

  int tid = threadIdx.x;
  int wv = tid >> 6, lane = tid & 63, col = lane & 15, quad = lane >> 4;
  int bi = blockIdx.x;
  int b = (bi & 7) * 128 + (bi >> 5);   // same-b heads -> same XCD
  int h = (bi >> 3) & 3;

  const __bf16* wH = wF + (size_t)h * 12288;
#define WG(t, nt, kc) (*(const bf16x8*)&wH[(((t) * 2 + (nt)) * 4 + (kc)) * 512 + lane * 8])

  const float* xb = x + (size_t)b * (196 * 128);
  const float scale = 0.17677669529663687f;   // 32^-0.5

  s16x4 qb[4][2];   // persisted q B-frags for this wave's tiles

  // ---- Stage B: per owned tile, load x once; compute k,v -> LDS and q -> regs
#pragma unroll
  for (int i = 0; i < 4; i++) {
    int qt = wv + i * NW;
    if (qt < 13) {
      int row = qt * 16 + col;
      const float* ap = xb + (size_t)(row < 196 ? row : 0) * 128 + quad * 8;
      bf16x8 xf[4];
#pragma unroll
      for (int kc = 0; kc < 4; kc++) xf[kc] = load_a_f32(ap + kc * 32);
#pragma unroll
      for (int nt = 0; nt < 2; nt++) {       // k, swapped: D[od][token]
        f32x4 acc = {0.f, 0.f, 0.f, 0.f};
#pragma unroll
        for (int kc = 0; kc < 4; kc++) acc = MFMA32(WG(1, nt, kc), xf[kc], acc);
        bf16x4 pk;
#pragma unroll
        for (int r = 0; r < 4; r++) pk[r] = (__bf16)acc[r];
        *(bf16x4*)&k_s[row * KS + nt * 16 + quad * 4] = pk;
      }
#pragma unroll
      for (int nt = 0; nt < 2; nt++) {       // v, normal: D[token][od] -> vT_s[od][token]
        f32x4 acc = {0.f, 0.f, 0.f, 0.f};
#pragma unroll
        for (int kc = 0; kc < 4; kc++) acc = MFMA32(xf[kc], WG(2, nt, kc), acc);
        bf16x4 pk;
#pragma unroll
        for (int r = 0; r < 4; r++) pk[r] = (__bf16)acc[r];
        *(bf16x4*)&vT_s[(nt * 16 + col) * VS + qt * 16 + quad * 4] = pk;
      }
#pragma unroll
      for (int nt = 0; nt < 2; nt++) {       // q, swapped -> registers
        f32x4 acc = {0.f, 0.f, 0.f, 0.f};
#pragma unroll
        for (int kc = 0; kc < 4; kc++) acc = MFMA32(WG(0, nt, kc), xf[kc], acc);
        bf16x4 pk;
#pragma unroll
        for (int r = 0; r < 4; r++) pk[r] = (__bf16)(acc[r] * scale);
        qb[i][nt] = __builtin_bit_cast(s16x4, pk);
      }
    }
  }
  __syncthreads();

  // ---- q-phase: per owned tile, S^T -> exp -> PV, all register-resident
#pragma unroll
  for (int i = 0; i < 4; i++) {
    int qt = wv + i * NW;
    if (qt < 13) {
      int qi = qt * 16 + col;
      const __bf16* brow = biasT + ((size_t)(h * 208 + qi)) * 208 + quad * 4;
      bf16x4 bl[13];
#pragma unroll
      for (int kt = 0; kt < 13; kt++) bl[kt] = *(const bf16x4*)(brow + kt * 16);

      float sum = 0.f;
      s16x4 pp[13];
#pragma unroll
      for (int kt = 0; kt < 13; kt++) {
        s16x4 ka0 = *(const s16x4*)&k_s[(kt * 16 + col) * KS + quad * 4];
        s16x4 ka1 = *(const s16x4*)&k_s[(kt * 16 + col) * KS + 16 + quad * 4];
        f32x4 acc = {0.f, 0.f, 0.f, 0.f};
        acc = MFMAX16(ka0, qb[i][0], acc);
        acc = MFMAX16(ka1, qb[i][1], acc);
        bf16x4 pk;
#pragma unroll
        for (int r = 0; r < 4; r++) {
          float e = __expf(acc[r] + (float)bl[kt][r]);
          if (kt == 12 && quad != 0) e = 0.f;   // kj >= 196 masked
          sum += e;
          pk[r] = (__bf16)e;
        }
        pp[kt] = __builtin_bit_cast(s16x4, pk);
      }
      sum += __shfl_xor(sum, 16);
      sum += __shfl_xor(sum, 32);
      float inv = 1.f / sum;

      // O^T = V^T P^T, split even/odd accumulator chains
      f32x4 o0a = {0.f,0.f,0.f,0.f}, o0b = {0.f,0.f,0.f,0.f};
      f32x4 o1a = {0.f,0.f,0.f,0.f}, o1b = {0.f,0.f,0.f,0.f};
#pragma unroll
      for (int kt = 0; kt < 13; kt++) {
        s16x4 va0 = *(const s16x4*)&vT_s[col * VS + kt * 16 + quad * 4];
        s16x4 va1 = *(const s16x4*)&vT_s[(16 + col) * VS + kt * 16 + quad * 4];
        if (kt & 1) { o0b = MFMAX16(va0, pp[kt], o0b); o1b = MFMAX16(va1, pp[kt], o1b); }
        else        { o0a = MFMAX16(va0, pp[kt], o0a); o1a = MFMAX16(va1, pp[kt], o1a); }
      }
      if (qi < 196) {
        __bf16* og = Og + ((size_t)b * 196 + qi) * 128 + h * 32;
        bf16x4 s0, s1;
#pragma unroll
        for (int r = 0; r < 4; r++) {
          s0[r] = (__bf16)((o0a[r] + o0b[r]) * inv);
          s1[r] = (__bf16)((o1a[r] + o1b[r]) * inv);
        }
        *(bf16x4*)&og[quad * 4]      = s0;
        *(bf16x4*)&og[16 + quad * 4] = s1;
      }
    }
  }
#undef WG
}

// ---------------- output projection: out = O @ wproj + bproj -----------------
// LDS-free, barrier-free: each wave owns one 16-row M-tile.
__launch_bounds__(256, 4)
__global__ void k_proj(const __bf16* __restrict__ Og, const __bf16* __restrict__ wpT,
                       const float* __restrict__ bproj, float* __restrict__ out) {
  int tid = threadIdx.x, wv = tid >> 6, lane = tid & 63, col = lane & 15, quad = lane >> 4;
  size_t rb = (size_t)blockIdx.x * 64 + wv * 16;   // wave's 16-row tile
  const __bf16* arow = Og + (rb + col) * 128 + quad * 8;
  bf16x8 af[4];
#pragma unroll
  for (int kc = 0; kc < 4; kc++) af[kc] = *(const bf16x8*)(arow + kc * 32);
#pragma unroll
  for (int nt = 0; nt < 8; nt++) {          // swapped: D[od][token]
    f32x4 acc = {0.f, 0.f, 0.f, 0.f};
#pragma unroll
    for (int kc = 0; kc < 4; kc++)
      acc = MFMA32(*(const bf16x8*)&wpT[(size_t)(nt * 16 + col) * 128 + kc * 32 + quad * 8],
                   af[kc], acc);
    int od = nt * 16 + quad * 4;
    float4 bp = *(const float4*)&bproj[od];
    float4 st = { acc[0] + bp.x, acc[1] + bp.y, acc[2] + bp.z, acc[3] + bp.w };
    *(float4*)&out[(rb + col) * 128 + od] = st;
  }
}

extern "C" void kernel_launch(void* const* d_in, const int* in_sizes, int n_in,
                              void* d_out, int out_size, void* d_ws, size_t ws_size,
                              hipStream_t stream) {
  const float* x     = (const float*)d_in[0];
  const float* wq    = (const float*)d_in[1];
  const float* wkv   = (const float*)d_in[2];
  const float* wproj = (const float*)d_in[3];
  const float* bproj = (const float*)d_in[4];
  const float* pp_w  = (const float*)d_in[5];
  const float* pp_b  = (const float*)d_in[6];
  const float* ln1_g = (const float*)d_in[7];
  const float* ln1_b = (const float*)d_in[8];
  const float* l1_w  = (const float*)d_in[9];
  const float* l1_b  = (const float*)d_in[10];
  const float* ln2_g = (const float*)d_in[11];
  const float* ln2_b = (const float*)d_in[12];
  const float* l2_w  = (const float*)d_in[13];
  const float* l2_b  = (const float*)d_in[14];
  const float* ln3_g = (const float*)d_in[15];
  const float* ln3_b = (const float*)d_in[16];
  const float* l3_w  = (const float*)d_in[17];
  const float* l3_b  = (const float*)d_in[18];
  float* out = (float*)d_out;

  char* ws = (char*)d_ws;
  __bf16* wF    = (__bf16*)ws;                  //  98304 B  [4][3][2][4][64][8]
  __bf16* wpT   = (__bf16*)(ws + 98304);        //  32768 B  [128][128]
  __bf16* biasT = (__bf16*)(ws + 131072);       // 346112 B  [4][208][208]
  __bf16* Og    = (__bf16*)(ws + 477184);       // 51380224 B [B][196][128]

  k_prep<<<257, 256, 0, stream>>>(wq, wkv, wproj, pp_w, pp_b,
                                  ln1_g, ln1_b, l1_w, l1_b,
                                  ln2_g, ln2_b, l2_w, l2_b,
                                  ln3_g, ln3_b, l3_w, l3_b,
                                  wF, wpT, biasT);
  k_attn<<<4096, 256, 0, stream>>>(x, wF, biasT, Og);
  k_proj<<<3136, 256, 0, stream>>>(Og, wpT, bproj, out);
}